// Round 10
// baseline (314.520 us; speedup 1.0000x reference)
//
#include <hip/hip_runtime.h>
#include <hip/hip_bf16.h>
#include <stdint.h>

// Problem constants
#define MB_  8
#define NQ_  256
#define NKV_ 4096
#define E_   1024
#define H_   16
#define D_   64

typedef __bf16 bf16x8 __attribute__((ext_vector_type(8)));
typedef float  f32x4  __attribute__((ext_vector_type(4)));
typedef unsigned short u16;
typedef unsigned short u16x8 __attribute__((ext_vector_type(8)));

#define MFMA16(a,b,c) __builtin_amdgcn_mfma_f32_16x16x32_bf16((a),(b),(c),0,0,0)

__device__ __forceinline__ u16 f2bf(float f) {
  uint32_t u = __float_as_uint(f);
  u += 0x7fffu + ((u >> 16) & 1u);   // RNE (no NaNs in this workload)
  return (u16)(u >> 16);
}

__device__ __forceinline__ void gload_lds16(const void* g, void* l) {
  __builtin_amdgcn_global_load_lds(
      (const __attribute__((address_space(1))) void*)g,
      (__attribute__((address_space(3))) void*)l, 16, 0, 0);
}

// Stage a 128-row x 128-byte bf16 tile (row stride ldbytes) into LDS.
// Swizzle via the GLOBAL source address (rule #21).
__device__ __forceinline__ void stage_tile(const char* __restrict__ g, int ldbytes,
                                           char* lds, int t) {
  int srcCB = (((t & 7) ^ ((t >> 3) & 7)) << 4);
  const char* gp = g + (long long)(t >> 3) * ldbytes + srcCB;
  char* lp = lds + ((t >> 6) << 10);
#pragma unroll
  for (int i = 0; i < 4; ++i) {
    gload_lds16(gp + (long long)(32 * i) * ldbytes, lp + i * 4096);
  }
}

__device__ __forceinline__ bf16x8 read_frag(const char* lds, int r, int cb) {
  return *(const bf16x8*)(lds + r * 128 + (cb ^ ((r & 7) << 4)));
}

// ---------------------------------------------------------------------------
// Generic NT GEMM (128x128 tile, BK=64, 256 thr). MODE 0: bf16 C.
// MODE 2: split-K x4 f32 partials (z = ks*8 + m). Used for Qproj + PV.
// ---------------------------------------------------------------------------
template <int MODE>
__global__ __launch_bounds__(256, 2) void gemm_nt(
    const u16* __restrict__ A, const u16* __restrict__ Bt, void* __restrict__ Cv,
    int lda, int ldb, int ldc, int K,
    long long sA, long long sB, long long sC) {
  __shared__ __align__(16) char smA[16384];
  __shared__ __align__(16) char smB[16384];
  int zz = blockIdx.z;
  int b = (MODE == 2) ? (zz & 7) : zz;
  int ks = (MODE == 2) ? (zz >> 3) : 0;
  long long koff = (long long)ks * 1024;

  unsigned nwg = gridDim.x * gridDim.y;
  unsigned orig = blockIdx.y * gridDim.x + blockIdx.x;
  unsigned cpx = nwg >> 3;
  unsigned swz = (orig & 7) * cpx + (orig >> 3);
  unsigned bx = swz % gridDim.x, by = swz / gridDim.x;

  const char* Ap = (const char*)(A + (long long)b * sA + (long long)by * 128 * lda + koff);
  const char* Bp = (const char*)(Bt + (long long)b * sB + (long long)bx * 128 * ldb + koff);

  int t = threadIdx.x, lane = t & 63;
  int wm = t >> 7, wn = (t >> 6) & 1;
  int rl = lane & 15, kq = lane >> 4;

  f32x4 acc[4][4];
#pragma unroll
  for (int i = 0; i < 4; ++i)
#pragma unroll
    for (int j = 0; j < 4; ++j) acc[i][j] = (f32x4){0.f, 0.f, 0.f, 0.f};

  int ldab = lda * 2, ldbb = ldb * 2;
  for (int k0 = 0; k0 < K; k0 += 64) {
    stage_tile(Ap + k0 * 2, ldab, smA, t);
    stage_tile(Bp + k0 * 2, ldbb, smB, t);
    __syncthreads();
    bf16x8 af[4][2], bf[4][2];
#pragma unroll
    for (int f = 0; f < 4; ++f)
#pragma unroll
      for (int ksl = 0; ksl < 2; ++ksl) {
        af[f][ksl] = read_frag(smA, wm * 64 + f * 16 + rl, ksl * 64 + kq * 16);
        bf[f][ksl] = read_frag(smB, wn * 64 + f * 16 + rl, ksl * 64 + kq * 16);
      }
#pragma unroll
    for (int fm = 0; fm < 4; ++fm)
#pragma unroll
      for (int fn = 0; fn < 4; ++fn) {
        acc[fm][fn] = MFMA16(af[fm][0], bf[fn][0], acc[fm][fn]);
        acc[fm][fn] = MFMA16(af[fm][1], bf[fn][1], acc[fm][fn]);
      }
    __syncthreads();
  }

#pragma unroll
  for (int fm = 0; fm < 4; ++fm)
#pragma unroll
    for (int fn = 0; fn < 4; ++fn)
#pragma unroll
      for (int j = 0; j < 4; ++j) {
        int row = by * 128 + wm * 64 + fm * 16 + kq * 4 + j;
        int col = bx * 128 + wn * 64 + fn * 16 + rl;
        if (MODE == 0) {
          ((u16*)Cv)[(long long)b * sC + (long long)row * ldc + col] = f2bf(acc[fm][fn][j]);
        } else {
          ((float*)Cv)[((long long)(ks * 8 + b)) * sC + (long long)row * ldc + col] =
              acc[fm][fn][j];
        }
      }
}

// ---------------------------------------------------------------------------
// gemm256f v2: 256x256 tile, BK=32, 512 threads (8 waves 2Mx4N), A ingested
// as FLOAT32 (in-register convert inside the pipeline).
// R9 bug: B was 1-ahead (one MFMA cluster ~200cyc cannot cover ~600cyc mem
// latency -> 122us). v2 restores 2-AHEAD for BOTH operands:
//   B (bf16): gload_lds, 2-ahead, 4 buffers (identical to proven gemm256).
//   A (f32):  global_load->regs 2-ahead; A(ts+2) issued into rSet[ts&1]
//             (free: A(ts) was LDS-written at end of ts-1; end-of-ts write is
//             from the OTHER parity set -> no WAR window). 2 LDS buffers.
// Per step ts: issue [B(ts+2) (2 ops), A(ts+2) (4 ops)] (order pinned by
// sched_barrier(0)); ds_read+MFMA; wait vmcnt(6) = leave exactly
// {B(ts+2),A(ts+2)} in flight, retiring B(ts+1)+A(ts+1); write A(ts+1);
// lgkmcnt(0); s_barrier. vmcnt(0) only in the 2-step tail.
// LDS = 2x16K(A) + 4x16K(B) = 96 KB.
// 64B-row swizzle: c16 ^= (row>>1)&3 (reads 2-way on banks = free).
// ---------------------------------------------------------------------------
__device__ __forceinline__ void stageB32(const char* __restrict__ g, int ldbytes,
                                         char* ldsbuf, int t, long long koffB) {
  int w = t >> 6, lane = t & 63;
#pragma unroll
  for (int i = 0; i < 2; ++i) {
    int c = w + i * 8;
    int slot = c * 64 + lane;
    int row = slot >> 2, c16 = slot & 3;
    int srcc = (c16 ^ ((row >> 1) & 3)) << 4;
    gload_lds16(g + (long long)row * ldbytes + koffB + srcc, ldsbuf + c * 1024);
  }
}

__device__ __forceinline__ void loadA32(const float* __restrict__ Apf, int lda,
                                        int t, int k0, float4 r[4]) {
  int row = t >> 1, kh = (t & 1) * 16;
  const float* p = Apf + (long long)row * lda + k0 + kh;
#pragma unroll
  for (int i = 0; i < 4; ++i) r[i] = *(const float4*)(p + i * 4);
}

__device__ __forceinline__ void writeA32(char* bufA, int t, const float4 r[4]) {
  int row = t >> 1, kh = t & 1;
  int sw = (row >> 1) & 3;
#pragma unroll
  for (int i = 0; i < 2; ++i) {
    float4 a = r[i * 2], b = r[i * 2 + 1];
    u16x8 v;
    v[0] = f2bf(a.x); v[1] = f2bf(a.y); v[2] = f2bf(a.z); v[3] = f2bf(a.w);
    v[4] = f2bf(b.x); v[5] = f2bf(b.y); v[6] = f2bf(b.z); v[7] = f2bf(b.w);
    int c16 = kh * 2 + i;
    *(u16x8*)(bufA + row * 64 + ((c16 ^ sw) << 4)) = v;
  }
}

__device__ __forceinline__ bf16x8 frag32(const char* ldsbuf, int r, int kq) {
  return *(const bf16x8*)(ldsbuf + r * 64 + ((kq ^ ((r >> 1) & 3)) << 4));
}

__global__ __launch_bounds__(512, 1) void gemm256f(
    const float* __restrict__ A, const u16* __restrict__ Bt, u16* __restrict__ C,
    int lda, int ldb, int ldc, int K) {
  extern __shared__ char lds[];   // A0,A1 @0,16K; B0..B3 @32K..96K

  unsigned nwg = gridDim.x * gridDim.y;
  unsigned orig = blockIdx.y * gridDim.x + blockIdx.x;
  unsigned cpx = nwg >> 3;
  unsigned swz = (orig & 7) * cpx + (orig >> 3);
  unsigned bx = swz % gridDim.x, by = swz / gridDim.x;

  const float* Apf = A + (long long)by * 256 * lda;
  const char* Bp = (const char*)(Bt + (long long)bx * 256 * ldb);
  int ldbb = ldb * 2;

  int t = threadIdx.x, lane = t & 63;
  int wid = t >> 6, wm = wid >> 2, wn = wid & 3;
  int rl = lane & 15, kq = lane >> 4;

  char* bufA0 = lds;
  char* bufA1 = lds + 16384;
  char* bufB = lds + 32768;   // 4 x 16384

  f32x4 acc[8][4];
#pragma unroll
  for (int i = 0; i < 8; ++i)
#pragma unroll
    for (int j = 0; j < 4; ++j) acc[i][j] = (f32x4){0.f, 0.f, 0.f, 0.f};

  float4 rEven[4], rOdd[4];

  // prologue: B(0),B(1); A(0)->rEven, A(1)->rOdd; retire through A(0);
  // write A(0); publish.
  stageB32(Bp, ldbb, bufB, t, 0);
  stageB32(Bp, ldbb, bufB + 16384, t, 64);
  __builtin_amdgcn_sched_barrier(0);
  loadA32(Apf, lda, t, 0, rEven);
  loadA32(Apf, lda, t, 32, rOdd);
  asm volatile("s_waitcnt vmcnt(4)" ::: "memory");   // leave A(1) in flight
  writeA32(bufA0, t, rEven);
  asm volatile("s_waitcnt lgkmcnt(0)" ::: "memory");
  asm volatile("s_barrier" ::: "memory");

  int NT = K >> 5;   // 32
  for (int ts = 0; ts < NT; ts += 2) {
    // ---- even step ts: compute from bufA0 / bufB[ts&3]
    if (ts + 2 < NT) {
      stageB32(Bp, ldbb, bufB + ((ts + 2) & 3) * 16384, t, (long long)(ts + 2) << 6);
      __builtin_amdgcn_sched_barrier(0);
      loadA32(Apf, lda, t, (ts + 2) << 5, rEven);   // rEven free: A(ts) already in LDS
    }
    {
      const char* bB = bufB + (ts & 3) * 16384;
      bf16x8 af[8], bv[4];
#pragma unroll
      for (int fr = 0; fr < 8; ++fr) af[fr] = frag32(bufA0, wm * 128 + fr * 16 + rl, kq);
#pragma unroll
      for (int fc = 0; fc < 4; ++fc) bv[fc] = frag32(bB, wn * 64 + fc * 16 + rl, kq);
      __builtin_amdgcn_s_setprio(1);
#pragma unroll
      for (int fr = 0; fr < 8; ++fr)
#pragma unroll
        for (int fc = 0; fc < 4; ++fc)
          acc[fr][fc] = MFMA16(af[fr], bv[fc], acc[fr][fc]);
      __builtin_amdgcn_s_setprio(0);
    }
    if (ts + 2 < NT)
      asm volatile("s_waitcnt vmcnt(6)" ::: "memory");  // retire B(ts+1)+A(ts+1)
    else
      asm volatile("s_waitcnt vmcnt(0)" ::: "memory");  // tail drain
    if (ts + 1 < NT) {
      writeA32(bufA1, t, rOdd);                         // A(ts+1)
      asm volatile("s_waitcnt lgkmcnt(0)" ::: "memory");
    }
    asm volatile("s_barrier" ::: "memory");
    if (ts + 1 >= NT) break;

    // ---- odd step ts+1: compute from bufA1 / bufB[(ts+1)&3]
    if (ts + 3 < NT) {
      stageB32(Bp, ldbb, bufB + ((ts + 3) & 3) * 16384, t, (long long)(ts + 3) << 6);
      __builtin_amdgcn_sched_barrier(0);
      loadA32(Apf, lda, t, (ts + 3) << 5, rOdd);
    }
    {
      const char* bB = bufB + ((ts + 1) & 3) * 16384;
      bf16x8 af[8], bv[4];
#pragma unroll
      for (int fr = 0; fr < 8; ++fr) af[fr] = frag32(bufA1, wm * 128 + fr * 16 + rl, kq);
#pragma unroll
      for (int fc = 0; fc < 4; ++fc) bv[fc] = frag32(bB, wn * 64 + fc * 16 + rl, kq);
      __builtin_amdgcn_s_setprio(1);
#pragma unroll
      for (int fr = 0; fr < 8; ++fr)
#pragma unroll
        for (int fc = 0; fc < 4; ++fc)
          acc[fr][fc] = MFMA16(af[fr], bv[fc], acc[fr][fc]);
      __builtin_amdgcn_s_setprio(0);
    }
    if (ts + 3 < NT)
      asm volatile("s_waitcnt vmcnt(6)" ::: "memory");  // retire B(ts+2)+A(ts+2)
    else
      asm volatile("s_waitcnt vmcnt(0)" ::: "memory");
    if (ts + 2 < NT) {
      writeA32(bufA0, t, rEven);                        // A(ts+2)
      asm volatile("s_waitcnt lgkmcnt(0)" ::: "memory");
    }
    asm volatile("s_barrier" ::: "memory");
  }

  // Epilogue. C/D layout: col = lane&15, row = (lane>>4)*4 + reg  [m89]
#pragma unroll
  for (int fr = 0; fr < 8; ++fr)
#pragma unroll
    for (int fc = 0; fc < 4; ++fc)
#pragma unroll
      for (int j = 0; j < 4; ++j) {
        int row = by * 256 + wm * 128 + fr * 16 + kq * 4 + j;
        int col = bx * 256 + wn * 64 + fc * 16 + rl;
        C[(long long)row * ldc + col] = f2bf(acc[fr][fc][j]);
      }
}

// ---------------------------------------------------------------------------
// Merged: zq passthrough copy (output 0) + PV split-K combine (output 1).
// ---------------------------------------------------------------------------
__global__ void pv_combine_copy(const float* __restrict__ part, const float* __restrict__ xq,
                                const float* __restrict__ zq, float* __restrict__ out0,
                                float* __restrict__ out1) {
  int bid = blockIdx.x;
  if (bid < 2048) {
    int i = bid * 256 + threadIdx.x;
    ((float4*)out0)[i] = ((const float4*)zq)[i];
  } else {
    int i = (bid - 2048) * 256 + threadIdx.x;
    float4 s = ((const float4*)xq)[i];
#pragma unroll
    for (int k = 0; k < 4; ++k) {
      float4 p = ((const float4*)(part + (long long)k * 2097152))[i];
      s.x += p.x; s.y += p.y; s.z += p.z; s.w += p.w;
    }
    ((float4*)out1)[i] = s;
  }
}

// ---------------------------------------------------------------------------
// Pass 1: tile-structured row sums of exp(S), no max shift (scores ~N(0,1)
// by construction; f32 sumexp headroom ~30 orders).
// grid = (kt=32, qt=2, z=16: m=z>>1, hhalf=z&1), block = 256 (2x2 waves).
// ---------------------------------------------------------------------------
__global__ __launch_bounds__(256, 4) void attn_stats(
    const u16* __restrict__ qg, const u16* __restrict__ kg,
    float* __restrict__ lstP) {
  __shared__ __align__(16) char smQ[16384];
  __shared__ __align__(16) char smK[16384];
  int kt = blockIdx.x, qt = blockIdx.y;
  int m = blockIdx.z >> 1, hh = blockIdx.z & 1;
  int t = threadIdx.x, lane = t & 63;
  int wm = t >> 7, wn = (t >> 6) & 1;
  int rl = lane & 15, kq = lane >> 4;

  const char* qbase = (const char*)(qg + ((long long)(m * NQ_ + qt * 128)) * 1024);
  const char* kbase = (const char*)(kg + ((long long)(m * NKV_ + kt * 128)) * 1024);

  for (int hi = 0; hi < 8; ++hi) {
    int h = hh * 8 + hi;
    stage_tile(qbase + h * 128, 2048, smQ, t);
    stage_tile(kbase + h * 128, 2048, smK, t);
    __syncthreads();
    bf16x8 kf[4][2], qf[4][2];
#pragma unroll
    for (int f = 0; f < 4; ++f)
#pragma unroll
      for (int ksl = 0; ksl < 2; ++ksl) {
        kf[f][ksl] = read_frag(smK, wm * 64 + f * 16 + rl, ksl * 64 + kq * 16);
        qf[f][ksl] = read_frag(smQ, wn * 64 + f * 16 + rl, ksl * 64 + kq * 16);
      }
    float rs[4] = {0.f, 0.f, 0.f, 0.f};
#pragma unroll
    for (int fm = 0; fm < 4; ++fm)
#pragma unroll
      for (int fn = 0; fn < 4; ++fn) {
        f32x4 sc = (f32x4){0.f, 0.f, 0.f, 0.f};
        sc = MFMA16(kf[fm][0], qf[fn][0], sc);
        sc = MFMA16(kf[fm][1], qf[fn][1], sc);
        rs[fn] += (__expf(sc[0]) + __expf(sc[1])) + (__expf(sc[2]) + __expf(sc[3]));
      }
#pragma unroll
    for (int fn = 0; fn < 4; ++fn) {
      float v = rs[fn];
      v += __shfl_xor(v, 16);
      v += __shfl_xor(v, 32);
      if (lane < 16) {
        int q = qt * 128 + wn * 64 + fn * 16 + rl;
        lstP[(long long)(kt * 2 + wm) * 32768 + ((m * H_ + h) << 8) + q] = v;
      }
    }
    __syncthreads();
  }
}

// ---------------------------------------------------------------------------
// Merge the 64 (kt x wm) partial sums. Fixed order -> deterministic.
// ---------------------------------------------------------------------------
__global__ void stats_combine(const float* __restrict__ lp, float* __restrict__ lst) {
  int i = blockIdx.x * 256 + threadIdx.x;
  float s = 0.f;
#pragma unroll
  for (int k = 0; k < 64; ++k) s += lp[(long long)k * 32768 + i];
  lst[i] = s;
}

// ---------------------------------------------------------------------------
// Pass 2: Pbar[m,q,k] = sum_h (hw[h]/l[m,h,q]) * exp(s_h), bf16 out.
// grid = (kt=32, qt=2, m=8), block = 256.
// ---------------------------------------------------------------------------
__global__ __launch_bounds__(256, 2) void pbar_kernel(
    const u16* __restrict__ qg, const u16* __restrict__ kg,
    const float* __restrict__ lstat,
    const float* __restrict__ rawhw, u16* __restrict__ Pbar) {
  __shared__ __align__(16) char smQ[16384];
  __shared__ __align__(16) char smK[16384];
  __shared__ float scf[2048];
  int kt = blockIdx.x, qt = blockIdx.y, m = blockIdx.z;
  int q0 = qt * 128, k0 = kt * 128;
  int t = threadIdx.x, lane = t & 63;
  int wm = t >> 7, wn = (t >> 6) & 1;
  int rl = lane & 15, kq = lane >> 4;

  float hm = -1e30f;
  for (int i = 0; i < H_; ++i) hm = fmaxf(hm, rawhw[i]);
  float hs = 0.f, hw[H_];
  for (int i = 0; i < H_; ++i) { hw[i] = __expf(rawhw[i] - hm); hs += hw[i]; }
  float hinv = 1.f / hs;
  for (int idx = t; idx < 2048; idx += 256) {
    int h = idx >> 7, r = idx & 127;
    scf[idx] = hw[h] * hinv / lstat[((m * H_ + h) << 8) + q0 + r];
  }

  f32x4 pacc[4][4];
#pragma unroll
  for (int i = 0; i < 4; ++i)
#pragma unroll
    for (int j = 0; j < 4; ++j) pacc[i][j] = (f32x4){0.f, 0.f, 0.f, 0.f};

  const char* qbase = (const char*)(qg + ((long long)(m * NQ_ + q0)) * 1024);
  const char* kbase = (const char*)(kg + ((long long)(m * NKV_ + k0)) * 1024);

  for (int h = 0; h < H_; ++h) {
    stage_tile(qbase + h * 128, 2048, smQ, t);
    stage_tile(kbase + h * 128, 2048, smK, t);
    __syncthreads();  // also orders the scf writes above (first iter)
    bf16x8 af[4][2], bfr[4][2];
#pragma unroll
    for (int f = 0; f < 4; ++f)
#pragma unroll
      for (int ksl = 0; ksl < 2; ++ksl) {
        af[f][ksl] = read_frag(smQ, wm * 64 + f * 16 + rl, ksl * 64 + kq * 16);
        bfr[f][ksl] = read_frag(smK, wn * 64 + f * 16 + rl, ksl * 64 + kq * 16);
      }
#pragma unroll
    for (int fm = 0; fm < 4; ++fm) {
      int rbase = wm * 64 + fm * 16 + kq * 4;
      float cf0 = scf[(h << 7) + rbase + 0];
      float cf1 = scf[(h << 7) + rbase + 1];
      float cf2 = scf[(h << 7) + rbase + 2];
      float cf3 = scf[(h << 7) + rbase + 3];
#pragma unroll
      for (int fn = 0; fn < 4; ++fn) {
        f32x4 sc = (f32x4){0.f, 0.f, 0.f, 0.f};
        sc = MFMA16(af[fm][0], bfr[fn][0], sc);
        sc = MFMA16(af[fm][1], bfr[fn][1], sc);
        pacc[fm][fn][0] += cf0 * __expf(sc[0]);
        pacc[fm][fn][1] += cf1 * __expf(sc[1]);
        pacc[fm][fn][2] += cf2 * __expf(sc[2]);
        pacc[fm][fn][3] += cf3 * __expf(sc[3]);
      }
    }
    __syncthreads();
  }
#pragma unroll
  for (int fm = 0; fm < 4; ++fm)
#pragma unroll
    for (int fn = 0; fn < 4; ++fn)
#pragma unroll
      for (int j = 0; j < 4; ++j) {
        int row = q0 + wm * 64 + fm * 16 + kq * 4 + j;
        int col = k0 + wn * 64 + fn * 16 + rl;
        Pbar[(((long long)m * NQ_ + row) << 12) + col] = f2bf(pacc[fm][fn][j]);
      }
}

// ---------------------------------------------------------------------------
// Merged prep (zkv convert fused into gemm256f):
//   [0, 1024):    zq f32->bf16 (8 elem/thread)
//   [1024, 1280): Wq 64x64 transpose tiles (alpha = 0.125, folds SCALE)
//   [1280, 1536): Wk tiles
//   [1536, 9728): xkv tiles (8 batches x 64 r-tiles x 16 c-tiles)
// ---------------------------------------------------------------------------
__global__ void prep_kernel(const float* __restrict__ zq, u16* __restrict__ zqb,
                            const float* __restrict__ Wq, u16* __restrict__ WqT,
                            const float* __restrict__ Wk, u16* __restrict__ WkT,
                            const float* __restrict__ xkv, u16* __restrict__ xkvT) {
  __shared__ float tile[64][65];
  int bid = blockIdx.x;
  if (bid < 1024) {
    long long i = (long long)bid * 256 + threadIdx.x;
    const float4* p = (const float4*)zq + i * 2;
    float4 a = p[0], b = p[1];
    u16x8 v;
    v[0] = f2bf(a.x); v[1] = f2bf(a.y); v[2] = f2bf(a.z); v[3] = f2bf(a.w);
    v[4] = f2bf(b.x); v[5] = f2bf(b.y); v[6] = f2bf(b.z); v[7] = f2bf(b.w);
    *(u16x8*)(zqb + i * 8) = v;
    return;
  }
  const float* in; u16* out; int R, C; float alpha; int r0, c0;
  if (bid < 1280) {
    int id = bid - 1024;
    in = Wq; out = WqT; R = 1024; C = 1024; alpha = 0.125f;
    r0 = (id & 15) * 64; c0 = (id >> 4) * 64;
  } else if (bid < 1536) {
    int id = bid - 1280;
    in = Wk; out = WkT; R = 1024; C = 1024; alpha = 1.0f;
    r0 = (id & 15) * 64; c0 = (id >> 4) * 64;
  } else {
    int id = bid - 1536;
    int bz = id >> 10, rem = id & 1023;
    in = xkv + (long long)bz * NKV_ * E_;
    out = xkvT + (long long)bz * NKV_ * E_;
    R = NKV_; C = E_; alpha = 1.0f;
    r0 = (rem & 63) * 64; c0 = (rem >> 6) * 64;
  }
  int t = threadIdx.x;
  int rr = t >> 4, c4 = t & 15;
#pragma unroll
  for (int i = 0; i < 4; ++i) {
    float4 v = *(const float4*)(in + (long long)(r0 + rr + i * 16) * C + c0 + c4 * 4);
    float* d = &tile[rr + i * 16][c4 * 4];
    d[0] = v.x; d[1] = v.y; d[2] = v.z; d[3] = v.w;
  }
  __syncthreads();
  int cc = t >> 3, r8 = t & 7;
#pragma unroll
  for (int i = 0; i < 2; ++i) {
    int c = cc + i * 32;
    u16x8 v;
#pragma unroll
    for (int j = 0; j < 8; ++j) v[j] = f2bf(alpha * tile[r8 * 8 + j][c]);
    *(u16x8*)(out + (long long)(c0 + c) * R + r0 + r8 * 8) = v;
  }
}

// ---------------------------------------------------------------------------
extern "C" void kernel_launch(void* const* d_in, const int* in_sizes, int n_in,
                              void* d_out, int out_size, void* d_ws, size_t ws_size,
                              hipStream_t stream) {
  const float* zq  = (const float*)d_in[0];
  const float* zkv = (const float*)d_in[1];
  const float* xq  = (const float*)d_in[2];
  const float* xkv = (const float*)d_in[3];
  const float* Wq  = (const float*)d_in[4];
  const float* Wk  = (const float*)d_in[5];
  const float* rhw = (const float*)d_in[6];
  float* out = (float*)d_out;

  // Workspace layout (bytes). Total need: ~172 MB.
  char* ws = (char*)d_ws;
  u16* WqT  = (u16*)(ws);                      //  2 MB  [1024][1024] (x0.125 folded)
  u16* WkT  = (u16*)(ws + (2ull << 20));       //  2 MB
  u16* zqb  = (u16*)(ws + (4ull << 20));       //  4 MB  [2048][1024]
  u16* qb   = (u16*)(ws + (8ull << 20));       //  4 MB  [2048][1024] (pre-scaled)
  u16* kb   = (u16*)(ws + (12ull << 20));      // 64 MB  [32768][1024]
  u16* xkvT = (u16*)(ws + (76ull << 20));      // 64 MB  [8][1024][4096]
  char* zr  = ws + (140ull << 20);             // 64 MB region:
  u16* Pbar = (u16*)zr;                        //   Pbar [8][256][4096] (16 MB)
  float* lst  = (float*)(zr + (18ull << 20));  //   final sumexp (128 KB)
  float* lstP = (float*)(zr + (20ull << 20));  //   partial sumexp [64][32768] (8 MB)
  float* pvP  = (float*)(zr + (28ull << 20));  //   PV split-K partials (32 MB)

  // allow 96 KB dynamic LDS for gemm256f (idempotent, non-stream call)
  (void)hipFuncSetAttribute((const void*)gemm256f,
                            hipFuncAttributeMaxDynamicSharedMemorySize, 98304);

  // 1. dtype converts (zkv NOT converted — gemm256f ingests f32 directly)
  prep_kernel<<<9728, 256, 0, stream>>>(zq, zqb, Wq, WqT, Wk, WkT, xkv, xkvT);

  // 2. projections: Qproj on 128^2; Kproj on the f32-A 256^2 2-ahead pipeline
  gemm_nt<0><<<dim3(8, 16, 1), 256, 0, stream>>>(zqb, WqT, qb,
                                                 1024, 1024, 1024, 1024, 0, 0, 0);
  gemm256f<<<dim3(4, 128, 1), 512, 98304, stream>>>(zkv, WkT, kb, 1024, 1024, 1024, 1024);

  // 3. softmax denominators
  attn_stats<<<dim3(32, 2, 16), 256, 0, stream>>>(qb, kb, lstP);
  stats_combine<<<128, 256, 0, stream>>>(lstP, lst);

  // 4. head-collapsed probabilities
  pbar_kernel<<<dim3(32, 2, 8), 256, 0, stream>>>(qb, kb, lst, rhw, Pbar);

  // 5. PV split-K x4 -> f32 partials, then combine with residual + zq copy
  gemm_nt<2><<<dim3(8, 2, 32), 256, 0, stream>>>(Pbar, xkvT, pvP,
                                                 4096, 4096, 1024, 1024,
                                                 256LL * 4096, 1024LL * 4096,
                                                 256LL * 1024);
  pv_combine_copy<<<4096, 256, 0, stream>>>(pvP, xq, zq, out,
                                            out + (long long)MB_ * NQ_ * E_);
}

// Round 11
// 300.166 us; speedup vs baseline: 1.0478x; 1.0478x over previous
//
#include <hip/hip_runtime.h>
#include <hip/hip_bf16.h>
#include <stdint.h>

// Problem constants
#define MB_  8
#define NQ_  256
#define NKV_ 4096
#define E_   1024
#define H_   16
#define D_   64

typedef __bf16 bf16x8 __attribute__((ext_vector_type(8)));
typedef float  f32x4  __attribute__((ext_vector_type(4)));
typedef unsigned short u16;
typedef unsigned short u16x8 __attribute__((ext_vector_type(8)));

#define MFMA16(a,b,c) __builtin_amdgcn_mfma_f32_16x16x32_bf16((a),(b),(c),0,0,0)

__device__ __forceinline__ u16 f2bf(float f) {
  uint32_t u = __float_as_uint(f);
  u += 0x7fffu + ((u >> 16) & 1u);   // RNE (no NaNs in this workload)
  return (u16)(u >> 16);
}

__device__ __forceinline__ void gload_lds16(const void* g, void* l) {
  __builtin_amdgcn_global_load_lds(
      (const __attribute__((address_space(1))) void*)g,
      (__attribute__((address_space(3))) void*)l, 16, 0, 0);
}

// Stage a 128-row x 128-byte bf16 tile (row stride ldbytes) into LDS.
// Swizzle via the GLOBAL source address (rule #21): LDS byte (row,cb) holds
// source (row, cb ^ ((row&7)<<4)).
// NOTE (R5/R9/R10 post-mortems): fusing f32->bf16 conversion into GEMM
// staging regressed 3x (R5, serial) and +70us (R9/R10, even with 2-ahead
// counted-vmcnt) — in-pipe convert at 1 block/CU cannot hide its latency.
// Keep global_load_lds bf16 staging; converts live in prep_kernel.
__device__ __forceinline__ void stage_tile(const char* __restrict__ g, int ldbytes,
                                           char* lds, int t) {
  int srcCB = (((t & 7) ^ ((t >> 3) & 7)) << 4);
  const char* gp = g + (long long)(t >> 3) * ldbytes + srcCB;
  char* lp = lds + ((t >> 6) << 10);
#pragma unroll
  for (int i = 0; i < 4; ++i) {
    gload_lds16(gp + (long long)(32 * i) * ldbytes, lp + i * 4096);
  }
}

__device__ __forceinline__ bf16x8 read_frag(const char* lds, int r, int cb) {
  return *(const bf16x8*)(lds + r * 128 + (cb ^ ((r & 7) << 4)));
}

// ---------------------------------------------------------------------------
// Generic NT GEMM (128x128 tile, BK=64, 256 thr). MODE 0: bf16 C.
// MODE 2: split-K x4 f32 partials (z = ks*8 + m). Used for Qproj + PV.
// ---------------------------------------------------------------------------
template <int MODE>
__global__ __launch_bounds__(256, 2) void gemm_nt(
    const u16* __restrict__ A, const u16* __restrict__ Bt, void* __restrict__ Cv,
    int lda, int ldb, int ldc, int K,
    long long sA, long long sB, long long sC) {
  __shared__ __align__(16) char smA[16384];
  __shared__ __align__(16) char smB[16384];
  int zz = blockIdx.z;
  int b = (MODE == 2) ? (zz & 7) : zz;
  int ks = (MODE == 2) ? (zz >> 3) : 0;
  long long koff = (long long)ks * 1024;

  unsigned nwg = gridDim.x * gridDim.y;
  unsigned orig = blockIdx.y * gridDim.x + blockIdx.x;
  unsigned cpx = nwg >> 3;
  unsigned swz = (orig & 7) * cpx + (orig >> 3);
  unsigned bx = swz % gridDim.x, by = swz / gridDim.x;

  const char* Ap = (const char*)(A + (long long)b * sA + (long long)by * 128 * lda + koff);
  const char* Bp = (const char*)(Bt + (long long)b * sB + (long long)bx * 128 * ldb + koff);

  int t = threadIdx.x, lane = t & 63;
  int wm = t >> 7, wn = (t >> 6) & 1;
  int rl = lane & 15, kq = lane >> 4;

  f32x4 acc[4][4];
#pragma unroll
  for (int i = 0; i < 4; ++i)
#pragma unroll
    for (int j = 0; j < 4; ++j) acc[i][j] = (f32x4){0.f, 0.f, 0.f, 0.f};

  int ldab = lda * 2, ldbb = ldb * 2;
  for (int k0 = 0; k0 < K; k0 += 64) {
    stage_tile(Ap + k0 * 2, ldab, smA, t);
    stage_tile(Bp + k0 * 2, ldbb, smB, t);
    __syncthreads();
    bf16x8 af[4][2], bf[4][2];
#pragma unroll
    for (int f = 0; f < 4; ++f)
#pragma unroll
      for (int ksl = 0; ksl < 2; ++ksl) {
        af[f][ksl] = read_frag(smA, wm * 64 + f * 16 + rl, ksl * 64 + kq * 16);
        bf[f][ksl] = read_frag(smB, wn * 64 + f * 16 + rl, ksl * 64 + kq * 16);
      }
#pragma unroll
    for (int fm = 0; fm < 4; ++fm)
#pragma unroll
      for (int fn = 0; fn < 4; ++fn) {
        acc[fm][fn] = MFMA16(af[fm][0], bf[fn][0], acc[fm][fn]);
        acc[fm][fn] = MFMA16(af[fm][1], bf[fn][1], acc[fm][fn]);
      }
    __syncthreads();
  }

#pragma unroll
  for (int fm = 0; fm < 4; ++fm)
#pragma unroll
    for (int fn = 0; fn < 4; ++fn)
#pragma unroll
      for (int j = 0; j < 4; ++j) {
        int row = by * 128 + wm * 64 + fm * 16 + kq * 4 + j;
        int col = bx * 128 + wn * 64 + fn * 16 + rl;
        if (MODE == 0) {
          ((u16*)Cv)[(long long)b * sC + (long long)row * ldc + col] = f2bf(acc[fm][fn][j]);
        } else {
          ((float*)Cv)[((long long)(ks * 8 + b)) * sC + (long long)row * ldc + col] =
              acc[fm][fn][j];
        }
      }
}

// ---------------------------------------------------------------------------
// gemm256 (R8-proven): 256x256 tile, BK=32, 512 threads (8 waves 2Mx4N),
// quad-buffered 128 KB LDS, counted-vmcnt pipeline (T4), raw s_barrier,
// prefetch 2 K-steps ahead, setprio (T5). Used for Kproj (bf16 in).
// ---------------------------------------------------------------------------
__device__ __forceinline__ void stage32(const char* __restrict__ g, int ldbytes,
                                        char* ldsbuf, int t, long long koffB) {
  int w = t >> 6, lane = t & 63;
#pragma unroll
  for (int i = 0; i < 2; ++i) {
    int c = w + i * 8;                 // 16 chunks of 1 KB = 16 KB tile
    int slot = c * 64 + lane;          // linear LDS 16B-slot
    int row = slot >> 2, c16 = slot & 3;
    int srcc = (c16 ^ ((row >> 1) & 3)) << 4;
    gload_lds16(g + (long long)row * ldbytes + koffB + srcc,
                ldsbuf + c * 1024);    // wave-uniform dest; HW adds lane*16
  }
}

__device__ __forceinline__ bf16x8 frag32(const char* ldsbuf, int r, int kq) {
  return *(const bf16x8*)(ldsbuf + r * 64 + ((kq ^ ((r >> 1) & 3)) << 4));
}

__global__ __launch_bounds__(512, 2) void gemm256(
    const u16* __restrict__ A, const u16* __restrict__ Bt, u16* __restrict__ C,
    int lda, int ldb, int ldc, int K) {
  extern __shared__ char lds[];   // 4 bufs x (A 16KB + B 16KB) = 128 KB

  unsigned nwg = gridDim.x * gridDim.y;
  unsigned orig = blockIdx.y * gridDim.x + blockIdx.x;
  unsigned cpx = nwg >> 3;
  unsigned swz = (orig & 7) * cpx + (orig >> 3);
  unsigned bx = swz % gridDim.x, by = swz / gridDim.x;

  const char* Ap = (const char*)(A + (long long)by * 256 * lda);
  const char* Bp = (const char*)(Bt + (long long)bx * 256 * ldb);
  int ldab = lda * 2, ldbb = ldb * 2;

  int t = threadIdx.x, lane = t & 63;
  int wid = t >> 6, wm = wid >> 2, wn = wid & 3;
  int rl = lane & 15, kq = lane >> 4;

  f32x4 acc[8][4];
#pragma unroll
  for (int i = 0; i < 8; ++i)
#pragma unroll
    for (int j = 0; j < 4; ++j) acc[i][j] = (f32x4){0.f, 0.f, 0.f, 0.f};

  // prologue: stage steps 0,1; wait own step-0 loads; collective barrier
  stage32(Ap, ldab, lds, t, 0);
  stage32(Bp, ldbb, lds + 16384, t, 0);
  stage32(Ap, ldab, lds + 32768, t, 64);
  stage32(Bp, ldbb, lds + 32768 + 16384, t, 64);
  asm volatile("s_waitcnt vmcnt(4)" ::: "memory");
  asm volatile("s_barrier" ::: "memory");

  int NT = K >> 5;
  for (int ts = 0; ts < NT; ++ts) {
    char* bufA = lds + (ts & 3) * 32768;
    char* bufB = bufA + 16384;
    if (ts + 2 < NT) {
      char* nb = lds + ((ts + 2) & 3) * 32768;
      stage32(Ap, ldab, nb, t, (long long)(ts + 2) << 6);
      stage32(Bp, ldbb, nb + 16384, t, (long long)(ts + 2) << 6);
    }
    bf16x8 af[8], bv[4];
#pragma unroll
    for (int fr = 0; fr < 8; ++fr) af[fr] = frag32(bufA, wm * 128 + fr * 16 + rl, kq);
#pragma unroll
    for (int fc = 0; fc < 4; ++fc) bv[fc] = frag32(bufB, wn * 64 + fc * 16 + rl, kq);
    __builtin_amdgcn_s_setprio(1);
#pragma unroll
    for (int fr = 0; fr < 8; ++fr)
#pragma unroll
      for (int fc = 0; fc < 4; ++fc)
        acc[fr][fc] = MFMA16(af[fr], bv[fc], acc[fr][fc]);
    __builtin_amdgcn_s_setprio(0);
    if (ts + 2 < NT)
      asm volatile("s_waitcnt vmcnt(4)" ::: "memory");  // keep next-next step in flight
    else
      asm volatile("s_waitcnt vmcnt(0)" ::: "memory");  // tail drain
    asm volatile("s_barrier" ::: "memory");
  }

  // Epilogue. C/D layout: col = lane&15, row = (lane>>4)*4 + reg  [m89]
#pragma unroll
  for (int fr = 0; fr < 8; ++fr)
#pragma unroll
    for (int fc = 0; fc < 4; ++fc)
#pragma unroll
      for (int j = 0; j < 4; ++j) {
        int row = by * 256 + wm * 128 + fr * 16 + kq * 4 + j;
        int col = bx * 256 + wn * 64 + fc * 16 + rl;
        C[(long long)row * ldc + col] = f2bf(acc[fr][fc][j]);
      }
}

// ---------------------------------------------------------------------------
// Merged: zq passthrough copy (output 0) + PV split-K combine (output 1).
// ---------------------------------------------------------------------------
__global__ void pv_combine_copy(const float* __restrict__ part, const float* __restrict__ xq,
                                const float* __restrict__ zq, float* __restrict__ out0,
                                float* __restrict__ out1) {
  int bid = blockIdx.x;
  if (bid < 2048) {
    int i = bid * 256 + threadIdx.x;
    ((float4*)out0)[i] = ((const float4*)zq)[i];
  } else {
    int i = (bid - 2048) * 256 + threadIdx.x;
    float4 s = ((const float4*)xq)[i];
#pragma unroll
    for (int k = 0; k < 4; ++k) {
      float4 p = ((const float4*)(part + (long long)k * 2097152))[i];
      s.x += p.x; s.y += p.y; s.z += p.z; s.w += p.w;
    }
    ((float4*)out1)[i] = s;
  }
}

// ---------------------------------------------------------------------------
// Pass 1: tile-structured row sums of exp(S), no max shift (scores ~N(0,1)
// by construction; f32 sumexp headroom ~30 orders).
// grid = (kt=32, qt=2, z=16: m=z>>1, hhalf=z&1), block = 256 (2x2 waves).
// ---------------------------------------------------------------------------
__global__ __launch_bounds__(256, 4) void attn_stats(
    const u16* __restrict__ qg, const u16* __restrict__ kg,
    float* __restrict__ lstP) {
  __shared__ __align__(16) char smQ[16384];
  __shared__ __align__(16) char smK[16384];
  int kt = blockIdx.x, qt = blockIdx.y;
  int m = blockIdx.z >> 1, hh = blockIdx.z & 1;
  int t = threadIdx.x, lane = t & 63;
  int wm = t >> 7, wn = (t >> 6) & 1;
  int rl = lane & 15, kq = lane >> 4;

  const char* qbase = (const char*)(qg + ((long long)(m * NQ_ + qt * 128)) * 1024);
  const char* kbase = (const char*)(kg + ((long long)(m * NKV_ + kt * 128)) * 1024);

  for (int hi = 0; hi < 8; ++hi) {
    int h = hh * 8 + hi;
    stage_tile(qbase + h * 128, 2048, smQ, t);
    stage_tile(kbase + h * 128, 2048, smK, t);
    __syncthreads();
    bf16x8 kf[4][2], qf[4][2];
#pragma unroll
    for (int f = 0; f < 4; ++f)
#pragma unroll
      for (int ksl = 0; ksl < 2; ++ksl) {
        kf[f][ksl] = read_frag(smK, wm * 64 + f * 16 + rl, ksl * 64 + kq * 16);
        qf[f][ksl] = read_frag(smQ, wn * 64 + f * 16 + rl, ksl * 64 + kq * 16);
      }
    float rs[4] = {0.f, 0.f, 0.f, 0.f};
#pragma unroll
    for (int fm = 0; fm < 4; ++fm)
#pragma unroll
      for (int fn = 0; fn < 4; ++fn) {
        f32x4 sc = (f32x4){0.f, 0.f, 0.f, 0.f};
        sc = MFMA16(kf[fm][0], qf[fn][0], sc);
        sc = MFMA16(kf[fm][1], qf[fn][1], sc);
        rs[fn] += (__expf(sc[0]) + __expf(sc[1])) + (__expf(sc[2]) + __expf(sc[3]));
      }
#pragma unroll
    for (int fn = 0; fn < 4; ++fn) {
      float v = rs[fn];
      v += __shfl_xor(v, 16);
      v += __shfl_xor(v, 32);
      if (lane < 16) {
        int q = qt * 128 + wn * 64 + fn * 16 + rl;
        lstP[(long long)(kt * 2 + wm) * 32768 + ((m * H_ + h) << 8) + q] = v;
      }
    }
    __syncthreads();
  }
}

// ---------------------------------------------------------------------------
// Merge the 64 (kt x wm) partial sums. Fixed order -> deterministic.
// ---------------------------------------------------------------------------
__global__ void stats_combine(const float* __restrict__ lp, float* __restrict__ lst) {
  int i = blockIdx.x * 256 + threadIdx.x;
  float s = 0.f;
#pragma unroll
  for (int k = 0; k < 64; ++k) s += lp[(long long)k * 32768 + i];
  lst[i] = s;
}

// ---------------------------------------------------------------------------
// Pass 2: Pbar[m,q,k] = sum_h (hw[h]/l[m,h,q]) * exp(s_h), bf16 out.
// grid = (kt=32, qt=2, m=8), block = 256.
// ---------------------------------------------------------------------------
__global__ __launch_bounds__(256, 2) void pbar_kernel(
    const u16* __restrict__ qg, const u16* __restrict__ kg,
    const float* __restrict__ lstat,
    const float* __restrict__ rawhw, u16* __restrict__ Pbar) {
  __shared__ __align__(16) char smQ[16384];
  __shared__ __align__(16) char smK[16384];
  __shared__ float scf[2048];
  int kt = blockIdx.x, qt = blockIdx.y, m = blockIdx.z;
  int q0 = qt * 128, k0 = kt * 128;
  int t = threadIdx.x, lane = t & 63;
  int wm = t >> 7, wn = (t >> 6) & 1;
  int rl = lane & 15, kq = lane >> 4;

  float hm = -1e30f;
  for (int i = 0; i < H_; ++i) hm = fmaxf(hm, rawhw[i]);
  float hs = 0.f, hw[H_];
  for (int i = 0; i < H_; ++i) { hw[i] = __expf(rawhw[i] - hm); hs += hw[i]; }
  float hinv = 1.f / hs;
  for (int idx = t; idx < 2048; idx += 256) {
    int h = idx >> 7, r = idx & 127;
    scf[idx] = hw[h] * hinv / lstat[((m * H_ + h) << 8) + q0 + r];
  }

  f32x4 pacc[4][4];
#pragma unroll
  for (int i = 0; i < 4; ++i)
#pragma unroll
    for (int j = 0; j < 4; ++j) pacc[i][j] = (f32x4){0.f, 0.f, 0.f, 0.f};

  const char* qbase = (const char*)(qg + ((long long)(m * NQ_ + q0)) * 1024);
  const char* kbase = (const char*)(kg + ((long long)(m * NKV_ + k0)) * 1024);

  for (int h = 0; h < H_; ++h) {
    stage_tile(qbase + h * 128, 2048, smQ, t);
    stage_tile(kbase + h * 128, 2048, smK, t);
    __syncthreads();  // also orders the scf writes above (first iter)
    bf16x8 af[4][2], bfr[4][2];
#pragma unroll
    for (int f = 0; f < 4; ++f)
#pragma unroll
      for (int ksl = 0; ksl < 2; ++ksl) {
        af[f][ksl] = read_frag(smQ, wm * 64 + f * 16 + rl, ksl * 64 + kq * 16);
        bfr[f][ksl] = read_frag(smK, wn * 64 + f * 16 + rl, ksl * 64 + kq * 16);
      }
#pragma unroll
    for (int fm = 0; fm < 4; ++fm) {
      int rbase = wm * 64 + fm * 16 + kq * 4;
      float cf0 = scf[(h << 7) + rbase + 0];
      float cf1 = scf[(h << 7) + rbase + 1];
      float cf2 = scf[(h << 7) + rbase + 2];
      float cf3 = scf[(h << 7) + rbase + 3];
#pragma unroll
      for (int fn = 0; fn < 4; ++fn) {
        f32x4 sc = (f32x4){0.f, 0.f, 0.f, 0.f};
        sc = MFMA16(af[fm][0], bfr[fn][0], sc);
        sc = MFMA16(af[fm][1], bfr[fn][1], sc);
        pacc[fm][fn][0] += cf0 * __expf(sc[0]);
        pacc[fm][fn][1] += cf1 * __expf(sc[1]);
        pacc[fm][fn][2] += cf2 * __expf(sc[2]);
        pacc[fm][fn][3] += cf3 * __expf(sc[3]);
      }
    }
    __syncthreads();
  }
#pragma unroll
  for (int fm = 0; fm < 4; ++fm)
#pragma unroll
    for (int fn = 0; fn < 4; ++fn)
#pragma unroll
      for (int j = 0; j < 4; ++j) {
        int row = q0 + wm * 64 + fm * 16 + kq * 4 + j;
        int col = k0 + wn * 64 + fn * 16 + rl;
        Pbar[(((long long)m * NQ_ + row) << 12) + col] = f2bf(pacc[fm][fn][j]);
      }
}

// ---------------------------------------------------------------------------
// Merged prep (R8 structure + phase-mixing permutation + nt stores for xkvT):
//   [0, 17408): cvt (zq first 1024 blocks, then zkv)
//   [17408, 17664): Wq 64x64 transpose tiles (alpha = 0.125, folds SCALE)
//   [17664, 17920): Wk tiles
//   [17920, 26112): xkv tiles (8 batches x 64 r-tiles x 16 c-tiles)
// Permutation wid = bid*5 mod 26112 (bijective: gcd(5, 2^9*3*17)=1) mixes
// the pure-streaming cvt phase with the LDS-transpose phase.
// xkvT stores are nontemporal (read only by PV, several large kernels later;
// guaranteed L2-dead) to keep L2 for zkvb/WkT which Kproj reads next.
// ---------------------------------------------------------------------------
__global__ void prep_kernel(const float* __restrict__ zq, u16* __restrict__ zqb,
                            const float* __restrict__ zkv, u16* __restrict__ zkvb,
                            const float* __restrict__ Wq, u16* __restrict__ WqT,
                            const float* __restrict__ Wk, u16* __restrict__ WkT,
                            const float* __restrict__ xkv, u16* __restrict__ xkvT) {
  __shared__ float tile[64][65];
  int bid = (int)(((long long)blockIdx.x * 5) % 26112);
  if (bid < 17408) {
    const float* in; u16* out; long long i;
    if (bid < 1024) { in = zq; out = zqb; i = (long long)bid * 256 + threadIdx.x; }
    else { in = zkv; out = zkvb; i = (long long)(bid - 1024) * 256 + threadIdx.x; }
    const float4* p = (const float4*)in + i * 2;
    float4 a = p[0], b = p[1];
    u16x8 v;
    v[0] = f2bf(a.x); v[1] = f2bf(a.y); v[2] = f2bf(a.z); v[3] = f2bf(a.w);
    v[4] = f2bf(b.x); v[5] = f2bf(b.y); v[6] = f2bf(b.z); v[7] = f2bf(b.w);
    *(u16x8*)(out + i * 8) = v;
    return;
  }
  const float* in; u16* out; int R, C; float alpha; int r0, c0; bool nts = false;
  if (bid < 17664) {
    int id = bid - 17408;
    in = Wq; out = WqT; R = 1024; C = 1024; alpha = 0.125f;
    r0 = (id & 15) * 64; c0 = (id >> 4) * 64;
  } else if (bid < 17920) {
    int id = bid - 17664;
    in = Wk; out = WkT; R = 1024; C = 1024; alpha = 1.0f;
    r0 = (id & 15) * 64; c0 = (id >> 4) * 64;
  } else {
    int id = bid - 17920;
    int bz = id >> 10, rem = id & 1023;
    in = xkv + (long long)bz * NKV_ * E_;
    out = xkvT + (long long)bz * NKV_ * E_;
    R = NKV_; C = E_; alpha = 1.0f;
    r0 = (rem & 63) * 64; c0 = (rem >> 6) * 64;
    nts = true;
  }
  int t = threadIdx.x;
  int rr = t >> 4, c4 = t & 15;
#pragma unroll
  for (int i = 0; i < 4; ++i) {
    float4 v = *(const float4*)(in + (long long)(r0 + rr + i * 16) * C + c0 + c4 * 4);
    float* d = &tile[rr + i * 16][c4 * 4];
    d[0] = v.x; d[1] = v.y; d[2] = v.z; d[3] = v.w;
  }
  __syncthreads();
  int cc = t >> 3, r8 = t & 7;
#pragma unroll
  for (int i = 0; i < 2; ++i) {
    int c = cc + i * 32;
    u16x8 v;
#pragma unroll
    for (int j = 0; j < 8; ++j) v[j] = f2bf(alpha * tile[r8 * 8 + j][c]);
    u16x8* dst = (u16x8*)(out + (long long)(c0 + c) * R + r0 + r8 * 8);
    if (nts) __builtin_nontemporal_store(v, dst);
    else *dst = v;
  }
}

// ---------------------------------------------------------------------------
extern "C" void kernel_launch(void* const* d_in, const int* in_sizes, int n_in,
                              void* d_out, int out_size, void* d_ws, size_t ws_size,
                              hipStream_t stream) {
  const float* zq  = (const float*)d_in[0];
  const float* zkv = (const float*)d_in[1];
  const float* xq  = (const float*)d_in[2];
  const float* xkv = (const float*)d_in[3];
  const float* Wq  = (const float*)d_in[4];
  const float* Wk  = (const float*)d_in[5];
  const float* rhw = (const float*)d_in[6];
  float* out = (float*)d_out;

  // Workspace layout (bytes). Total need: ~172 MB.
  char* ws = (char*)d_ws;
  u16* WqT  = (u16*)(ws);                      //  2 MB  [1024][1024] (x0.125 folded)
  u16* WkT  = (u16*)(ws + (2ull << 20));       //  2 MB
  u16* zqb  = (u16*)(ws + (4ull << 20));       //  4 MB  [2048][1024]
  u16* qb   = (u16*)(ws + (8ull << 20));       //  4 MB  [2048][1024] (pre-scaled)
  u16* kb   = (u16*)(ws + (12ull << 20));      // 64 MB  [32768][1024]
  u16* xkvT = (u16*)(ws + (76ull << 20));      // 64 MB  [8][1024][4096]
  char* zr  = ws + (140ull << 20);             // 64 MB region, dual-use:
  u16* zkvb = (u16*)zr;                        //   zkv bf16 (dead after Kproj)
  u16* Pbar = (u16*)zr;                        //   then Pbar [8][256][4096] (16 MB)
  float* lst  = (float*)(zr + (18ull << 20));  //   final sumexp (128 KB)
  float* lstP = (float*)(zr + (20ull << 20));  //   partial sumexp [64][32768] (8 MB)
  float* pvP  = (float*)(zr + (28ull << 20));  //   PV split-K partials (32 MB)

  // allow 128 KB dynamic LDS for gemm256 (idempotent, non-stream call)
  (void)hipFuncSetAttribute((const void*)gemm256,
                            hipFuncAttributeMaxDynamicSharedMemorySize, 131072);

  // 1. all dtype converts in one dispatch (phase-mixed)
  prep_kernel<<<26112, 256, 0, stream>>>(zq, zqb, zkv, zkvb, Wq, WqT, Wk, WkT, xkv, xkvT);

  // 2. projections: Qproj on 128^2; Kproj on the proven bf16 256^2 pipeline
  gemm_nt<0><<<dim3(8, 16, 1), 256, 0, stream>>>(zqb, WqT, qb,
                                                 1024, 1024, 1024, 1024, 0, 0, 0);
  gemm256<<<dim3(4, 128, 1), 512, 131072, stream>>>(zkvb, WkT, kb, 1024, 1024, 1024, 1024);

  // 3. softmax denominators
  attn_stats<<<dim3(32, 2, 16), 256, 0, stream>>>(qb, kb, lstP);
  stats_combine<<<128, 256, 0, stream>>>(lstP, lst);

  // 4. head-collapsed probabilities
  pbar_kernel<<<dim3(32, 2, 8), 256, 0, stream>>>(qb, kb, lst, rhw, Pbar);

  // 5. PV split-K x4 -> f32 partials, then combine with residual + zq copy
  gemm_nt<2><<<dim3(8, 2, 32), 256, 0, stream>>>(Pbar, xkvT, pvP,
                                                 4096, 4096, 1024, 1024,
                                                 256LL * 4096, 1024LL * 4096,
                                                 256LL * 1024);
  pv_combine_copy<<<4096, 256, 0, stream>>>(pvP, xq, zq, out,
                                            out + (long long)MB_ * NQ_ * E_);
}

// Round 13
// 297.461 us; speedup vs baseline: 1.0573x; 1.0091x over previous
//
#include <hip/hip_runtime.h>
#include <hip/hip_bf16.h>
#include <stdint.h>

// Problem constants
#define MB_  8
#define NQ_  256
#define NKV_ 4096
#define E_   1024
#define H_   16
#define D_   64

typedef __bf16 bf16x8 __attribute__((ext_vector_type(8)));
typedef float  f32x4  __attribute__((ext_vector_type(4)));
typedef unsigned short u16;
typedef unsigned short u16x8 __attribute__((ext_vector_type(8)));

#define MFMA16(a,b,c) __builtin_amdgcn_mfma_f32_16x16x32_bf16((a),(b),(c),0,0,0)

__device__ __forceinline__ u16 f2bf(float f) {
  uint32_t u = __float_as_uint(f);
  u += 0x7fffu + ((u >> 16) & 1u);   // RNE (no NaNs in this workload)
  return (u16)(u >> 16);
}

__device__ __forceinline__ u16x8 pack8(f32x4 a, f32x4 b) {
  u16x8 v;
  v[0] = f2bf(a[0]); v[1] = f2bf(a[1]); v[2] = f2bf(a[2]); v[3] = f2bf(a[3]);
  v[4] = f2bf(b[0]); v[5] = f2bf(b[1]); v[6] = f2bf(b[2]); v[7] = f2bf(b[3]);
  return v;
}

__device__ __forceinline__ void gload_lds16(const void* g, void* l) {
  __builtin_amdgcn_global_load_lds(
      (const __attribute__((address_space(1))) void*)g,
      (__attribute__((address_space(3))) void*)l, 16, 0, 0);
}

// Stage a 128-row x 128-byte bf16 tile (row stride ldbytes) into LDS.
// Swizzle via the GLOBAL source address (rule #21): LDS byte (row,cb) holds
// source (row, cb ^ ((row&7)<<4)).
// NOTE (R5/R9/R10): fusing f32->bf16 conversion into GEMM staging regressed
// every time (serial: 3x; 2-ahead counted-vmcnt: +70us at 1 block/CU).
// Converts stay in prep_kernel.
__device__ __forceinline__ void stage_tile(const char* __restrict__ g, int ldbytes,
                                           char* lds, int t) {
  int srcCB = (((t & 7) ^ ((t >> 3) & 7)) << 4);
  const char* gp = g + (long long)(t >> 3) * ldbytes + srcCB;
  char* lp = lds + ((t >> 6) << 10);
#pragma unroll
  for (int i = 0; i < 4; ++i) {
    gload_lds16(gp + (long long)(32 * i) * ldbytes, lp + i * 4096);
  }
}

__device__ __forceinline__ bf16x8 read_frag(const char* lds, int r, int cb) {
  return *(const bf16x8*)(lds + r * 128 + (cb ^ ((r & 7) << 4)));
}

// ---------------------------------------------------------------------------
// Generic NT GEMM (128x128 tile, BK=64, 256 thr). MODE 0: bf16 C.
// MODE 2: split-K x4 f32 partials (z = ks*8 + m), nontemporal C stores
//         (partials are read exactly once by pv_combine — L2-dead).
// ---------------------------------------------------------------------------
template <int MODE>
__global__ __launch_bounds__(256, 2) void gemm_nt(
    const u16* __restrict__ A, const u16* __restrict__ Bt, void* __restrict__ Cv,
    int lda, int ldb, int ldc, int K,
    long long sA, long long sB, long long sC) {
  __shared__ __align__(16) char smA[16384];
  __shared__ __align__(16) char smB[16384];
  int zz = blockIdx.z;
  int b = (MODE == 2) ? (zz & 7) : zz;
  int ks = (MODE == 2) ? (zz >> 3) : 0;
  long long koff = (long long)ks * 1024;

  unsigned nwg = gridDim.x * gridDim.y;
  unsigned orig = blockIdx.y * gridDim.x + blockIdx.x;
  unsigned cpx = nwg >> 3;
  unsigned swz = (orig & 7) * cpx + (orig >> 3);
  unsigned bx = swz % gridDim.x, by = swz / gridDim.x;

  const char* Ap = (const char*)(A + (long long)b * sA + (long long)by * 128 * lda + koff);
  const char* Bp = (const char*)(Bt + (long long)b * sB + (long long)bx * 128 * ldb + koff);

  int t = threadIdx.x, lane = t & 63;
  int wm = t >> 7, wn = (t >> 6) & 1;
  int rl = lane & 15, kq = lane >> 4;

  f32x4 acc[4][4];
#pragma unroll
  for (int i = 0; i < 4; ++i)
#pragma unroll
    for (int j = 0; j < 4; ++j) acc[i][j] = (f32x4){0.f, 0.f, 0.f, 0.f};

  int ldab = lda * 2, ldbb = ldb * 2;
  for (int k0 = 0; k0 < K; k0 += 64) {
    stage_tile(Ap + k0 * 2, ldab, smA, t);
    stage_tile(Bp + k0 * 2, ldbb, smB, t);
    __syncthreads();
    bf16x8 af[4][2], bf[4][2];
#pragma unroll
    for (int f = 0; f < 4; ++f)
#pragma unroll
      for (int ksl = 0; ksl < 2; ++ksl) {
        af[f][ksl] = read_frag(smA, wm * 64 + f * 16 + rl, ksl * 64 + kq * 16);
        bf[f][ksl] = read_frag(smB, wn * 64 + f * 16 + rl, ksl * 64 + kq * 16);
      }
#pragma unroll
    for (int fm = 0; fm < 4; ++fm)
#pragma unroll
      for (int fn = 0; fn < 4; ++fn) {
        acc[fm][fn] = MFMA16(af[fm][0], bf[fn][0], acc[fm][fn]);
        acc[fm][fn] = MFMA16(af[fm][1], bf[fn][1], acc[fm][fn]);
      }
    __syncthreads();
  }

#pragma unroll
  for (int fm = 0; fm < 4; ++fm)
#pragma unroll
    for (int fn = 0; fn < 4; ++fn)
#pragma unroll
      for (int j = 0; j < 4; ++j) {
        int row = by * 128 + wm * 64 + fm * 16 + kq * 4 + j;
        int col = bx * 128 + wn * 64 + fn * 16 + rl;
        if (MODE == 0) {
          ((u16*)Cv)[(long long)b * sC + (long long)row * ldc + col] = f2bf(acc[fm][fn][j]);
        } else {
          float* dst = (float*)Cv + ((long long)(ks * 8 + b)) * sC +
                       (long long)row * ldc + col;
          __builtin_nontemporal_store(acc[fm][fn][j], dst);
        }
      }
}

// ---------------------------------------------------------------------------
// gemm256 (R8-proven): 256x256 tile, BK=32, 512 threads (8 waves 2Mx4N),
// quad-buffered 128 KB LDS, counted-vmcnt pipeline (T4), raw s_barrier,
// prefetch 2 K-steps ahead, setprio (T5). Used for Kproj (bf16 in).
// ---------------------------------------------------------------------------
__device__ __forceinline__ void stage32(const char* __restrict__ g, int ldbytes,
                                        char* ldsbuf, int t, long long koffB) {
  int w = t >> 6, lane = t & 63;
#pragma unroll
  for (int i = 0; i < 2; ++i) {
    int c = w + i * 8;                 // 16 chunks of 1 KB = 16 KB tile
    int slot = c * 64 + lane;          // linear LDS 16B-slot
    int row = slot >> 2, c16 = slot & 3;
    int srcc = (c16 ^ ((row >> 1) & 3)) << 4;
    gload_lds16(g + (long long)row * ldbytes + koffB + srcc,
                ldsbuf + c * 1024);    // wave-uniform dest; HW adds lane*16
  }
}

__device__ __forceinline__ bf16x8 frag32(const char* ldsbuf, int r, int kq) {
  return *(const bf16x8*)(ldsbuf + r * 64 + ((kq ^ ((r >> 1) & 3)) << 4));
}

__global__ __launch_bounds__(512, 2) void gemm256(
    const u16* __restrict__ A, const u16* __restrict__ Bt, u16* __restrict__ C,
    int lda, int ldb, int ldc, int K) {
  extern __shared__ char lds[];   // 4 bufs x (A 16KB + B 16KB) = 128 KB

  unsigned nwg = gridDim.x * gridDim.y;
  unsigned orig = blockIdx.y * gridDim.x + blockIdx.x;
  unsigned cpx = nwg >> 3;
  unsigned swz = (orig & 7) * cpx + (orig >> 3);
  unsigned bx = swz % gridDim.x, by = swz / gridDim.x;

  const char* Ap = (const char*)(A + (long long)by * 256 * lda);
  const char* Bp = (const char*)(Bt + (long long)bx * 256 * ldb);
  int ldab = lda * 2, ldbb = ldb * 2;

  int t = threadIdx.x, lane = t & 63;
  int wid = t >> 6, wm = wid >> 2, wn = wid & 3;
  int rl = lane & 15, kq = lane >> 4;

  f32x4 acc[8][4];
#pragma unroll
  for (int i = 0; i < 8; ++i)
#pragma unroll
    for (int j = 0; j < 4; ++j) acc[i][j] = (f32x4){0.f, 0.f, 0.f, 0.f};

  // prologue: stage steps 0,1; wait own step-0 loads; collective barrier
  stage32(Ap, ldab, lds, t, 0);
  stage32(Bp, ldbb, lds + 16384, t, 0);
  stage32(Ap, ldab, lds + 32768, t, 64);
  stage32(Bp, ldbb, lds + 32768 + 16384, t, 64);
  asm volatile("s_waitcnt vmcnt(4)" ::: "memory");
  asm volatile("s_barrier" ::: "memory");

  int NT = K >> 5;
  for (int ts = 0; ts < NT; ++ts) {
    char* bufA = lds + (ts & 3) * 32768;
    char* bufB = bufA + 16384;
    if (ts + 2 < NT) {
      char* nb = lds + ((ts + 2) & 3) * 32768;
      stage32(Ap, ldab, nb, t, (long long)(ts + 2) << 6);
      stage32(Bp, ldbb, nb + 16384, t, (long long)(ts + 2) << 6);
    }
    bf16x8 af[8], bv[4];
#pragma unroll
    for (int fr = 0; fr < 8; ++fr) af[fr] = frag32(bufA, wm * 128 + fr * 16 + rl, kq);
#pragma unroll
    for (int fc = 0; fc < 4; ++fc) bv[fc] = frag32(bufB, wn * 64 + fc * 16 + rl, kq);
    __builtin_amdgcn_s_setprio(1);
#pragma unroll
    for (int fr = 0; fr < 8; ++fr)
#pragma unroll
      for (int fc = 0; fc < 4; ++fc)
        acc[fr][fc] = MFMA16(af[fr], bv[fc], acc[fr][fc]);
    __builtin_amdgcn_s_setprio(0);
    if (ts + 2 < NT)
      asm volatile("s_waitcnt vmcnt(4)" ::: "memory");  // keep next-next step in flight
    else
      asm volatile("s_waitcnt vmcnt(0)" ::: "memory");  // tail drain
    asm volatile("s_barrier" ::: "memory");
  }

  // Epilogue. C/D layout: col = lane&15, row = (lane>>4)*4 + reg  [m89]
#pragma unroll
  for (int fr = 0; fr < 8; ++fr)
#pragma unroll
    for (int fc = 0; fc < 4; ++fc)
#pragma unroll
      for (int j = 0; j < 4; ++j) {
        int row = by * 256 + wm * 128 + fr * 16 + kq * 4 + j;
        int col = bx * 256 + wn * 64 + fc * 16 + rl;
        C[(long long)row * ldc + col] = f2bf(acc[fr][fc][j]);
      }
}

// ---------------------------------------------------------------------------
// PV split-K combine: out1 = xq + sum of 4 partials. Fixed order. nt loads
// (pvP and xq are each read exactly once here).
// ---------------------------------------------------------------------------
__global__ void pv_combine(const float* __restrict__ part, const float* __restrict__ xq,
                           float* __restrict__ out1) {
  int i = blockIdx.x * 256 + threadIdx.x;
  f32x4 s = __builtin_nontemporal_load((const f32x4*)xq + i);
#pragma unroll
  for (int k = 0; k < 4; ++k) {
    f32x4 p = __builtin_nontemporal_load((const f32x4*)(part + (long long)k * 2097152) + i);
    s += p;
  }
  ((f32x4*)out1)[i] = s;
}

// ---------------------------------------------------------------------------
// Pass 1: tile-structured row sums of exp(S), no max shift (scores ~N(0,1)
// by construction; f32 sumexp headroom ~30 orders).
// grid = (kt=32, qt=2, z=16: m=z>>1, hhalf=z&1), block = 256 (2x2 waves).
// ---------------------------------------------------------------------------
__global__ __launch_bounds__(256, 4) void attn_stats(
    const u16* __restrict__ qg, const u16* __restrict__ kg,
    float* __restrict__ lstP) {
  __shared__ __align__(16) char smQ[16384];
  __shared__ __align__(16) char smK[16384];
  int kt = blockIdx.x, qt = blockIdx.y;
  int m = blockIdx.z >> 1, hh = blockIdx.z & 1;
  int t = threadIdx.x, lane = t & 63;
  int wm = t >> 7, wn = (t >> 6) & 1;
  int rl = lane & 15, kq = lane >> 4;

  const char* qbase = (const char*)(qg + ((long long)(m * NQ_ + qt * 128)) * 1024);
  const char* kbase = (const char*)(kg + ((long long)(m * NKV_ + kt * 128)) * 1024);

  for (int hi = 0; hi < 8; ++hi) {
    int h = hh * 8 + hi;
    stage_tile(qbase + h * 128, 2048, smQ, t);
    stage_tile(kbase + h * 128, 2048, smK, t);
    __syncthreads();
    bf16x8 kf[4][2], qf[4][2];
#pragma unroll
    for (int f = 0; f < 4; ++f)
#pragma unroll
      for (int ksl = 0; ksl < 2; ++ksl) {
        kf[f][ksl] = read_frag(smK, wm * 64 + f * 16 + rl, ksl * 64 + kq * 16);
        qf[f][ksl] = read_frag(smQ, wn * 64 + f * 16 + rl, ksl * 64 + kq * 16);
      }
    float rs[4] = {0.f, 0.f, 0.f, 0.f};
#pragma unroll
    for (int fm = 0; fm < 4; ++fm)
#pragma unroll
      for (int fn = 0; fn < 4; ++fn) {
        f32x4 sc = (f32x4){0.f, 0.f, 0.f, 0.f};
        sc = MFMA16(kf[fm][0], qf[fn][0], sc);
        sc = MFMA16(kf[fm][1], qf[fn][1], sc);
        rs[fn] += (__expf(sc[0]) + __expf(sc[1])) + (__expf(sc[2]) + __expf(sc[3]));
      }
#pragma unroll
    for (int fn = 0; fn < 4; ++fn) {
      float v = rs[fn];
      v += __shfl_xor(v, 16);
      v += __shfl_xor(v, 32);
      if (lane < 16) {
        int q = qt * 128 + wn * 64 + fn * 16 + rl;
        lstP[(long long)(kt * 2 + wm) * 32768 + ((m * H_ + h) << 8) + q] = v;
      }
    }
    __syncthreads();
  }
}

// ---------------------------------------------------------------------------
// Merge the 64 (kt x wm) partial sums. Fixed order -> deterministic.
// ---------------------------------------------------------------------------
__global__ void stats_combine(const float* __restrict__ lp, float* __restrict__ lst) {
  int i = blockIdx.x * 256 + threadIdx.x;
  float s = 0.f;
#pragma unroll
  for (int k = 0; k < 64; ++k) s += lp[(long long)k * 32768 + i];
  lst[i] = s;
}

// ---------------------------------------------------------------------------
// Pass 2: Pbar[m,q,k] = sum_h (hw[h]/l[m,h,q]) * exp(s_h), bf16 out.
// grid = (kt=32, qt=2, m=8), block = 256.
// ---------------------------------------------------------------------------
__global__ __launch_bounds__(256, 2) void pbar_kernel(
    const u16* __restrict__ qg, const u16* __restrict__ kg,
    const float* __restrict__ lstat,
    const float* __restrict__ rawhw, u16* __restrict__ Pbar) {
  __shared__ __align__(16) char smQ[16384];
  __shared__ __align__(16) char smK[16384];
  __shared__ float scf[2048];
  int kt = blockIdx.x, qt = blockIdx.y, m = blockIdx.z;
  int q0 = qt * 128, k0 = kt * 128;
  int t = threadIdx.x, lane = t & 63;
  int wm = t >> 7, wn = (t >> 6) & 1;
  int rl = lane & 15, kq = lane >> 4;

  float hm = -1e30f;
  for (int i = 0; i < H_; ++i) hm = fmaxf(hm, rawhw[i]);
  float hs = 0.f, hw[H_];
  for (int i = 0; i < H_; ++i) { hw[i] = __expf(rawhw[i] - hm); hs += hw[i]; }
  float hinv = 1.f / hs;
  for (int idx = t; idx < 2048; idx += 256) {
    int h = idx >> 7, r = idx & 127;
    scf[idx] = hw[h] * hinv / lstat[((m * H_ + h) << 8) + q0 + r];
  }

  f32x4 pacc[4][4];
#pragma unroll
  for (int i = 0; i < 4; ++i)
#pragma unroll
    for (int j = 0; j < 4; ++j) pacc[i][j] = (f32x4){0.f, 0.f, 0.f, 0.f};

  const char* qbase = (const char*)(qg + ((long long)(m * NQ_ + q0)) * 1024);
  const char* kbase = (const char*)(kg + ((long long)(m * NKV_ + k0)) * 1024);

  for (int h = 0; h < H_; ++h) {
    stage_tile(qbase + h * 128, 2048, smQ, t);
    stage_tile(kbase + h * 128, 2048, smK, t);
    __syncthreads();  // also orders the scf writes above (first iter)
    bf16x8 af[4][2], bfr[4][2];
#pragma unroll
    for (int f = 0; f < 4; ++f)
#pragma unroll
      for (int ksl = 0; ksl < 2; ++ksl) {
        af[f][ksl] = read_frag(smQ, wm * 64 + f * 16 + rl, ksl * 64 + kq * 16);
        bfr[f][ksl] = read_frag(smK, wn * 64 + f * 16 + rl, ksl * 64 + kq * 16);
      }
#pragma unroll
    for (int fm = 0; fm < 4; ++fm) {
      int rbase = wm * 64 + fm * 16 + kq * 4;
      float cf0 = scf[(h << 7) + rbase + 0];
      float cf1 = scf[(h << 7) + rbase + 1];
      float cf2 = scf[(h << 7) + rbase + 2];
      float cf3 = scf[(h << 7) + rbase + 3];
#pragma unroll
      for (int fn = 0; fn < 4; ++fn) {
        f32x4 sc = (f32x4){0.f, 0.f, 0.f, 0.f};
        sc = MFMA16(af[fm][0], bfr[fn][0], sc);
        sc = MFMA16(af[fm][1], bfr[fn][1], sc);
        pacc[fm][fn][0] += cf0 * __expf(sc[0]);
        pacc[fm][fn][1] += cf1 * __expf(sc[1]);
        pacc[fm][fn][2] += cf2 * __expf(sc[2]);
        pacc[fm][fn][3] += cf3 * __expf(sc[3]);
      }
    }
    __syncthreads();
  }
#pragma unroll
  for (int fm = 0; fm < 4; ++fm)
#pragma unroll
    for (int fn = 0; fn < 4; ++fn)
#pragma unroll
      for (int j = 0; j < 4; ++j) {
        int row = q0 + wm * 64 + fm * 16 + kq * 4 + j;
        int col = k0 + wn * 64 + fn * 16 + rl;
        Pbar[(((long long)m * NQ_ + row) << 12) + col] = f2bf(pacc[fm][fn][j]);
      }
}

// ---------------------------------------------------------------------------
// prep v3: wide-vector converts + nt hygiene (all nt accesses use ext_vector
// f32x4 — __builtin_nontemporal_* rejects HIP_vector_type float4).
// Identity block map. All streamed inputs nt-loaded (read-once); xkvT
// nt-stored (L2-dead until PV). zq blocks also write the f32 passthrough to
// out0 (zq read exactly once in the whole pipeline).
//   [0, 512):      zq -> zqb (bf16) + out0 (f32), 16 elem/thread
//   [512, 8704):   zkv -> zkvb, 16 elem/thread
//   [8704, 8960):  Wq 64x64 transpose tiles (alpha 0.125 folds SCALE)
//   [8960, 9216):  Wk tiles
//   [9216, 17408): xkv transpose tiles (nt stores)
// ---------------------------------------------------------------------------
__global__ void prep_kernel(const float* __restrict__ zq, u16* __restrict__ zqb,
                            float* __restrict__ out0,
                            const float* __restrict__ zkv, u16* __restrict__ zkvb,
                            const float* __restrict__ Wq, u16* __restrict__ WqT,
                            const float* __restrict__ Wk, u16* __restrict__ WkT,
                            const float* __restrict__ xkv, u16* __restrict__ xkvT) {
  __shared__ float tile[64][65];
  int bid = blockIdx.x;
  if (bid < 8704) {
    const float* in; u16* out; bool passthru; long long i;
    if (bid < 512) { in = zq; out = zqb; passthru = true; i = (long long)bid * 256 + threadIdx.x; }
    else { in = zkv; out = zkvb; passthru = false; i = (long long)(bid - 512) * 256 + threadIdx.x; }
    const f32x4* p = (const f32x4*)(in + i * 16);
    f32x4 a = __builtin_nontemporal_load(p);
    f32x4 b = __builtin_nontemporal_load(p + 1);
    f32x4 c = __builtin_nontemporal_load(p + 2);
    f32x4 d = __builtin_nontemporal_load(p + 3);
    if (passthru) {
      f32x4* o = (f32x4*)(out0 + i * 16);
      __builtin_nontemporal_store(a, o);
      __builtin_nontemporal_store(b, o + 1);
      __builtin_nontemporal_store(c, o + 2);
      __builtin_nontemporal_store(d, o + 3);
    }
    u16x8* q = (u16x8*)(out + i * 16);
    q[0] = pack8(a, b);
    q[1] = pack8(c, d);
    return;
  }
  const float* in; u16* out; int R, C; float alpha; int r0, c0; bool nts = false;
  if (bid < 8960) {
    int id = bid - 8704;
    in = Wq; out = WqT; R = 1024; C = 1024; alpha = 0.125f;
    r0 = (id & 15) * 64; c0 = (id >> 4) * 64;
  } else if (bid < 9216) {
    int id = bid - 8960;
    in = Wk; out = WkT; R = 1024; C = 1024; alpha = 1.0f;
    r0 = (id & 15) * 64; c0 = (id >> 4) * 64;
  } else {
    int id = bid - 9216;
    int bz = id >> 10, rem = id & 1023;
    in = xkv + (long long)bz * NKV_ * E_;
    out = xkvT + (long long)bz * NKV_ * E_;
    R = NKV_; C = E_; alpha = 1.0f;
    r0 = (rem & 63) * 64; c0 = (rem >> 6) * 64;
    nts = true;
  }
  int t = threadIdx.x;
  int rr = t >> 4, c4 = t & 15;
#pragma unroll
  for (int i = 0; i < 4; ++i) {
    f32x4 v = __builtin_nontemporal_load(
        (const f32x4*)(in + (long long)(r0 + rr + i * 16) * C + c0 + c4 * 4));
    float* d = &tile[rr + i * 16][c4 * 4];
    d[0] = v[0]; d[1] = v[1]; d[2] = v[2]; d[3] = v[3];
  }
  __syncthreads();
  int cc = t >> 3, r8 = t & 7;
#pragma unroll
  for (int i = 0; i < 2; ++i) {
    int c = cc + i * 32;
    u16x8 v;
#pragma unroll
    for (int j = 0; j < 8; ++j) v[j] = f2bf(alpha * tile[r8 * 8 + j][c]);
    u16x8* dst = (u16x8*)(out + (long long)(c0 + c) * R + r0 + r8 * 8);
    if (nts) __builtin_nontemporal_store(v, dst);
    else *dst = v;
  }
}

// ---------------------------------------------------------------------------
extern "C" void kernel_launch(void* const* d_in, const int* in_sizes, int n_in,
                              void* d_out, int out_size, void* d_ws, size_t ws_size,
                              hipStream_t stream) {
  const float* zq  = (const float*)d_in[0];
  const float* zkv = (const float*)d_in[1];
  const float* xq  = (const float*)d_in[2];
  const float* xkv = (const float*)d_in[3];
  const float* Wq  = (const float*)d_in[4];
  const float* Wk  = (const float*)d_in[5];
  const float* rhw = (const float*)d_in[6];
  float* out = (float*)d_out;

  // Workspace layout (bytes). Total need: ~172 MB.
  char* ws = (char*)d_ws;
  u16* WqT  = (u16*)(ws);                      //  2 MB  [1024][1024] (x0.125 folded)
  u16* WkT  = (u16*)(ws + (2ull << 20));       //  2 MB
  u16* zqb  = (u16*)(ws + (4ull << 20));       //  4 MB  [2048][1024]
  u16* qb   = (u16*)(ws + (8ull << 20));       //  4 MB  [2048][1024] (pre-scaled)
  u16* kb   = (u16*)(ws + (12ull << 20));      // 64 MB  [32768][1024]
  u16* xkvT = (u16*)(ws + (76ull << 20));      // 64 MB  [8][1024][4096]
  char* zr  = ws + (140ull << 20);             // 64 MB region, dual-use:
  u16* zkvb = (u16*)zr;                        //   zkv bf16 (dead after Kproj)
  u16* Pbar = (u16*)zr;                        //   then Pbar [8][256][4096] (16 MB)
  float* lst  = (float*)(zr + (18ull << 20));  //   final sumexp (128 KB)
  float* lstP = (float*)(zr + (20ull << 20));  //   partial sumexp [64][32768] (8 MB)
  float* pvP  = (float*)(zr + (28ull << 20));  //   PV split-K partials (32 MB)

  // allow 128 KB dynamic LDS for gemm256 (idempotent, non-stream call)
  (void)hipFuncSetAttribute((const void*)gemm256,
                            hipFuncAttributeMaxDynamicSharedMemorySize, 131072);

  // 1. all dtype converts + zq passthrough in one dispatch
  prep_kernel<<<17408, 256, 0, stream>>>(zq, zqb, out, zkv, zkvb,
                                         Wq, WqT, Wk, WkT, xkv, xkvT);

  // 2. projections: Qproj on 128^2; Kproj on the proven bf16 256^2 pipeline
  gemm_nt<0><<<dim3(8, 16, 1), 256, 0, stream>>>(zqb, WqT, qb,
                                                 1024, 1024, 1024, 1024, 0, 0, 0);
  gemm256<<<dim3(4, 128, 1), 512, 131072, stream>>>(zkvb, WkT, kb, 1024, 1024, 1024, 1024);

  // 3. softmax denominators
  attn_stats<<<dim3(32, 2, 16), 256, 0, stream>>>(qb, kb, lstP);
  stats_combine<<<128, 256, 0, stream>>>(lstP, lst);

  // 4. head-collapsed probabilities
  pbar_kernel<<<dim3(32, 2, 8), 256, 0, stream>>>(qb, kb, lst, rhw, Pbar);

  // 5. PV split-K x4 -> f32 partials (nt stores), then combine with residual
  gemm_nt<2><<<dim3(8, 2, 32), 256, 0, stream>>>(Pbar, xkvT, pvP,
                                                 4096, 4096, 1024, 1024,
                                                 256LL * 4096, 1024LL * 4096,
                                                 256LL * 1024);
  pv_combine<<<2048, 256, 0, stream>>>(pvP, xq, out + (long long)MB_ * NQ_ * E_);
}